// Round 2
// baseline (774.874 us; speedup 1.0000x reference)
//
#include <hip/hip_runtime.h>
#include <hip/hip_bf16.h>

// NGCF fused propagation, N=8192, D=64.
// out_user = leaky( invc[j]*Pu[j,0:64] + (item[j]*invc[j]*Pu[j,64:128])@W2 + user[j] )
// out_item = leaky( invr[i]*Pi[i,0:64] + (user[i]*invr[i]*Pi[i,64:128])@W2 + item[i] )
// Pi = adj @ Bt_item^T   (Bt_item[d][j] = invc[j]*[user@W1 | item][j][d])
// Pu = adj^T @ Bt_user^T (Bt_user[d][i] = invr[i]*[item@W1 | user][i][d])

#define LRELU_ALPHA 0.2f
constexpr int N = 8192;

typedef __attribute__((ext_vector_type(4))) float f32x4;
typedef __attribute__((ext_vector_type(8))) __bf16 bf16x8;

__device__ __forceinline__ unsigned short f2bf(float x) {
    unsigned u = __builtin_bit_cast(unsigned, x);
    u += 0x7fffu + ((u >> 16) & 1u);   // RNE
    return (unsigned short)(u >> 16);
}
__device__ __forceinline__ unsigned pk_bf16(float x, float y) {
    return (unsigned)f2bf(x) | ((unsigned)f2bf(y) << 16);
}
__device__ __forceinline__ f32x4 mfma16(uint4 a, uint4 b, f32x4 c) {
    return __builtin_amdgcn_mfma_f32_16x16x32_bf16(
        __builtin_bit_cast(bf16x8, a), __builtin_bit_cast(bf16x8, b), c, 0, 0, 0);
}

// ---------------- row/col sums of adjacency ----------------
__global__ __launch_bounds__(256) void sums_kernel(const float* __restrict__ adj,
                                                   float* __restrict__ rs,
                                                   float* __restrict__ cs) {
    const int tid = threadIdx.x;
    const int r0 = blockIdx.x * 32;
    __shared__ float rowsum[32];
    if (tid < 32) rowsum[tid] = 0.f;
    __syncthreads();
    float4 colacc[8];
#pragma unroll
    for (int c = 0; c < 8; ++c) colacc[c] = make_float4(0.f, 0.f, 0.f, 0.f);
    for (int r = 0; r < 32; ++r) {
        const float4* row = reinterpret_cast<const float4*>(adj + (size_t)(r0 + r) * N);
        float rp = 0.f;
#pragma unroll
        for (int c = 0; c < 8; ++c) {
            float4 v = row[tid + 256 * c];
            colacc[c].x += v.x; colacc[c].y += v.y;
            colacc[c].z += v.z; colacc[c].w += v.w;
            rp += (v.x + v.y) + (v.z + v.w);
        }
#pragma unroll
        for (int off = 32; off > 0; off >>= 1) rp += __shfl_down(rp, off, 64);
        if ((tid & 63) == 0) atomicAdd(&rowsum[r], rp);
    }
    __syncthreads();
    if (tid < 32) rs[r0 + tid] = rowsum[tid];
#pragma unroll
    for (int c = 0; c < 8; ++c) {
        int col = 4 * (tid + 256 * c);
        atomicAdd(&cs[col + 0], colacc[c].x);
        atomicAdd(&cs[col + 1], colacc[c].y);
        atomicAdd(&cs[col + 2], colacc[c].z);
        atomicAdd(&cs[col + 3], colacc[c].w);
    }
}

// ---------------- build the two RHS matrices (transposed, bf16) ----------------
__global__ __launch_bounds__(256) void prep_kernel(
    const float* __restrict__ user, const float* __restrict__ item,
    const float* __restrict__ W1, const float* __restrict__ rs, const float* __restrict__ cs,
    unsigned short* __restrict__ Bti, unsigned short* __restrict__ Btu) {
    __shared__ float W1s[64][65];
    __shared__ float ru[64][65];
    __shared__ float ri[64][65];
    __shared__ unsigned short tile[128][66];
    const int tid = threadIdx.x;
    const int j0 = blockIdx.x * 64;
    for (int t = tid; t < 64 * 64; t += 256) {
        W1s[t >> 6][t & 63] = W1[t];
        ru[t >> 6][t & 63] = user[(size_t)j0 * 64 + t];
        ri[t >> 6][t & 63] = item[(size_t)j0 * 64 + t];
    }
    __syncthreads();
    for (int pass = 0; pass < 2; ++pass) {
        for (int it = 0; it < 32; ++it) {
            int idx = tid + 256 * it;
            int d = idx & 127, jl = idx >> 7;
            float scale = (pass == 0) ? rsqrtf(cs[j0 + jl]) : rsqrtf(rs[j0 + jl]);
            float v;
            if (d < 64) {
                const float(*src)[65] = (pass == 0) ? ru : ri;  // src @ W1 half
                float acc = 0.f;
#pragma unroll
                for (int k = 0; k < 64; ++k) acc += src[jl][k] * W1s[k][d];
                v = acc;
            } else {
                const float(*src)[65] = (pass == 0) ? ri : ru;  // raw tgt-of-(S@tgt) half
                v = src[jl][d - 64];
            }
            tile[d][jl] = f2bf(v * scale);
        }
        __syncthreads();
        unsigned short* Bt = (pass == 0) ? Bti : Btu;
        for (int t = tid; t < 128 * 64; t += 256) {
            int d = t >> 6, jl = t & 63;
            Bt[(size_t)d * N + j0 + jl] = tile[d][jl];
        }
        __syncthreads();
    }
}

// ---------------- main MFMA GEMM: P += adj(^T) @ Bt^T ----------------
// TRANS=false: P_item rows = adj rows (contiguous-K A-frag loads)
// TRANS=true : P_user rows = adj cols (row-strided A-frag loads)
template <bool TRANS>
__global__ __launch_bounds__(256, 2) void gemm_kernel(
    const float* __restrict__ adj, const unsigned short* __restrict__ Bt,
    float* __restrict__ P) {
    const int lane = threadIdx.x & 63, wave = threadIdx.x >> 6;
    const int q = lane >> 4, lm = lane & 15;
    const int m0 = blockIdx.x * 64 + wave * 16;  // 16 output rows per wave
    const int k0 = blockIdx.y * 2048;            // split-K chunk
    f32x4 acc[8];
#pragma unroll
    for (int n = 0; n < 8; ++n) acc[n] = (f32x4){0.f, 0.f, 0.f, 0.f};
    const float* __restrict__ abase =
        TRANS ? (adj + (m0 + lm)) : (adj + (size_t)(m0 + lm) * N);
    const unsigned short* __restrict__ bb = Bt + (size_t)lm * N;
#pragma unroll 2
    for (int ks = 0; ks < 2048; ks += 32) {
        const int ka = k0 + ks + 8 * q;
        uint4 af;
        if (!TRANS) {
            float4 a0 = *reinterpret_cast<const float4*>(abase + ka);
            float4 a1 = *reinterpret_cast<const float4*>(abase + ka + 4);
            af.x = pk_bf16(a0.x, a0.y); af.y = pk_bf16(a0.z, a0.w);
            af.z = pk_bf16(a1.x, a1.y); af.w = pk_bf16(a1.z, a1.w);
        } else {
            float a[8];
#pragma unroll
            for (int jj = 0; jj < 8; ++jj) a[jj] = abase[(size_t)(ka + jj) * N];
            af.x = pk_bf16(a[0], a[1]); af.y = pk_bf16(a[2], a[3]);
            af.z = pk_bf16(a[4], a[5]); af.w = pk_bf16(a[6], a[7]);
        }
#pragma unroll
        for (int nt = 0; nt < 8; ++nt) {
            uint4 bf = *reinterpret_cast<const uint4*>(bb + (size_t)(16 * nt) * N + ka);
            acc[nt] = mfma16(af, bf, acc[nt]);
        }
    }
#pragma unroll
    for (int nt = 0; nt < 8; ++nt) {
#pragma unroll
        for (int r = 0; r < 4; ++r) {
            int row = m0 + q * 4 + r;          // C layout: row=(lane>>4)*4+reg
            int col = 16 * nt + lm;            //           col=lane&15
            atomicAdd(&P[(size_t)row * 128 + col], acc[nt][r]);
        }
    }
}

// ---------------- epilogue: scale, (g)@W2, +tgt, leaky, write ----------------
__global__ __launch_bounds__(256) void epilogue_kernel(
    const float* __restrict__ user, const float* __restrict__ item,
    const float* __restrict__ W2, const float* __restrict__ rs, const float* __restrict__ cs,
    const float* __restrict__ Pi, const float* __restrict__ Pu,
    float* __restrict__ out) {
    __shared__ float W2s[64][65];
    __shared__ float gi[4][64];
    __shared__ float gu[4][64];
    const int tid = threadIdx.x;
    for (int t = tid; t < 64 * 64; t += 256) W2s[t >> 6][t & 63] = W2[t];
    const int r4 = tid >> 6, d = tid & 63;
    for (int p = 0; p < 4; ++p) {
        const int row = blockIdx.x * 16 + p * 4 + r4;
        const float invr = rsqrtf(rs[row]);
        const float invc = rsqrtf(cs[row]);
        const float u_rd = user[(size_t)row * 64 + d];
        const float i_rd = item[(size_t)row * 64 + d];
        __syncthreads();
        gi[r4][d] = u_rd * invr * Pi[(size_t)row * 128 + 64 + d];
        gu[r4][d] = i_rd * invc * Pu[(size_t)row * 128 + 64 + d];
        __syncthreads();
        float vi = invr * Pi[(size_t)row * 128 + d] + i_rd;
        float vu = invc * Pu[(size_t)row * 128 + d] + u_rd;
#pragma unroll
        for (int e = 0; e < 64; ++e) {
            vi += gi[r4][e] * W2s[e][d];
            vu += gu[r4][e] * W2s[e][d];
        }
        vi = vi > 0.f ? vi : LRELU_ALPHA * vi;
        vu = vu > 0.f ? vu : LRELU_ALPHA * vu;
        out[(size_t)row * 64 + d] = vu;                        // updated_user (output 0)
        out[(size_t)N * 64 + (size_t)row * 64 + d] = vi;       // updated_item (output 1)
    }
}

extern "C" void kernel_launch(void* const* d_in, const int* in_sizes, int n_in,
                              void* d_out, int out_size, void* d_ws, size_t ws_size,
                              hipStream_t stream) {
    const float* user = (const float*)d_in[0];
    const float* item = (const float*)d_in[1];
    const float* adj  = (const float*)d_in[2];
    const float* W1   = (const float*)d_in[3];
    const float* W2   = (const float*)d_in[4];
    float* out = (float*)d_out;

    char* w = (char*)d_ws;
    float* Pi = (float*)w;  w += (size_t)N * 128 * 4;   // 4 MB
    float* Pu = (float*)w;  w += (size_t)N * 128 * 4;   // 4 MB
    float* rs = (float*)w;  w += (size_t)N * 4;
    float* cs = (float*)w;  w += (size_t)N * 4;
    unsigned short* Bti = (unsigned short*)w;  w += (size_t)N * 128 * 2;  // 2 MB
    unsigned short* Btu = (unsigned short*)w;                            // 2 MB

    // zero Pi, Pu, rs, cs (contiguous)
    (void)hipMemsetAsync(Pi, 0, ((size_t)2 * N * 128 + 2 * N) * 4, stream);

    sums_kernel<<<N / 32, 256, 0, stream>>>(adj, rs, cs);
    prep_kernel<<<N / 64, 256, 0, stream>>>(user, item, W1, rs, cs, Bti, Btu);
    gemm_kernel<false><<<dim3(N / 64, 4), 256, 0, stream>>>(adj, Bti, Pi);
    gemm_kernel<true ><<<dim3(N / 64, 4), 256, 0, stream>>>(adj, Btu, Pu);
    epilogue_kernel<<<N / 16, 256, 0, stream>>>(user, item, W2, rs, cs, Pi, Pu, out);
}

// Round 3
// 757.702 us; speedup vs baseline: 1.0227x; 1.0227x over previous
//
#include <hip/hip_runtime.h>
#include <hip/hip_bf16.h>

// NGCF fused propagation, N=8192, D=64.
// Pipeline:
//  pass1: read fp32 adj once -> rs, cs (row/col sums) + adjbf (bf16) + adjT (bf16 transposed)
//  prep : Bti[d][j] = invc[j]*[user@W1 | item][j][d] ; Btu[d][i] = invr[i]*[item@W1 | user][i][d]
//  gemm : Pi = adjbf @ Bti^T ; Pu = adjT @ Btu^T   (one launch, blockIdx.z selects)
//  epi  : out = leaky( inv*P[:,0:64] + (tgt_elem*inv*P[:,64:128])@W2 + tgt )

#define LRELU_ALPHA 0.2f
constexpr int N = 8192;
constexpr int KSPLIT = 8;

typedef __attribute__((ext_vector_type(4))) float f32x4;
typedef __attribute__((ext_vector_type(8))) __bf16 bf16x8;

__device__ __forceinline__ unsigned short f2bf(float x) {
    unsigned u = __builtin_bit_cast(unsigned, x);
    u += 0x7fffu + ((u >> 16) & 1u);   // RNE
    return (unsigned short)(u >> 16);
}
__device__ __forceinline__ f32x4 mfma16(uint4 a, uint4 b, f32x4 c) {
    return __builtin_amdgcn_mfma_f32_16x16x32_bf16(
        __builtin_bit_cast(bf16x8, a), __builtin_bit_cast(bf16x8, b), c, 0, 0, 0);
}

// ---------------- pass1: sums + bf16 copy + bf16 transpose ----------------
// 128x128 fp32 tile per block; 256 threads.
__global__ __launch_bounds__(256) void pass1_kernel(
    const float* __restrict__ adj,
    float* __restrict__ rs, float* __restrict__ cs,
    unsigned short* __restrict__ adjbf, unsigned short* __restrict__ adjT) {
    __shared__ unsigned short tile[128][132];   // pitch 132 ushorts
    __shared__ float rowsumL[128];
    __shared__ float4 colpart4[8][32];
    const int tid = threadIdx.x;
    const int g32 = tid >> 5;        // 0..7
    const int l32 = tid & 31;        // 0..31
    const int r0 = blockIdx.y * 128;
    const int c0 = blockIdx.x * 128;

    float4 colacc = make_float4(0.f, 0.f, 0.f, 0.f);
#pragma unroll 4
    for (int s = 0; s < 16; ++s) {
        const int row = s * 8 + g32;
        float4 v = *reinterpret_cast<const float4*>(adj + (size_t)(r0 + row) * N + c0 + l32 * 4);
        colacc.x += v.x; colacc.y += v.y; colacc.z += v.z; colacc.w += v.w;
        ushort4 b;
        b.x = f2bf(v.x); b.y = f2bf(v.y); b.z = f2bf(v.z); b.w = f2bf(v.w);
        *reinterpret_cast<ushort4*>(&tile[row][l32 * 4]) = b;
        *reinterpret_cast<ushort4*>(adjbf + (size_t)(r0 + row) * N + c0 + l32 * 4) = b;
        float rp = (v.x + v.y) + (v.z + v.w);
#pragma unroll
        for (int off = 16; off > 0; off >>= 1) rp += __shfl_down(rp, off, 32);
        if (l32 == 0) rowsumL[row] = rp;
    }
    colpart4[g32][l32] = colacc;
    __syncthreads();

    if (tid < 128) {
        atomicAdd(rs + r0 + tid, rowsumL[tid]);
        const float* cp = (const float*)colpart4;
        float s = 0.f;
#pragma unroll
        for (int w = 0; w < 8; ++w) s += cp[w * 128 + tid];
        atomicAdd(cs + c0 + tid, s);
    }

    // transposed write: out row j (= original col), contiguous in original row index
#pragma unroll 4
    for (int s = 0; s < 16; ++s) {
        const int j = s * 8 + g32;
        ushort4 b;
        b.x = tile[l32 * 4 + 0][j];
        b.y = tile[l32 * 4 + 1][j];
        b.z = tile[l32 * 4 + 2][j];
        b.w = tile[l32 * 4 + 3][j];
        *reinterpret_cast<ushort4*>(adjT + (size_t)(c0 + j) * N + r0 + l32 * 4) = b;
    }
}

// ---------------- build the two RHS matrices (transposed, bf16) ----------------
__global__ __launch_bounds__(256) void prep_kernel(
    const float* __restrict__ user, const float* __restrict__ item,
    const float* __restrict__ W1, const float* __restrict__ rs, const float* __restrict__ cs,
    unsigned short* __restrict__ Bti, unsigned short* __restrict__ Btu) {
    __shared__ float W1s[64][65];
    __shared__ float ru[64][65];
    __shared__ float ri[64][65];
    __shared__ unsigned short tile[128][66];
    const int tid = threadIdx.x;
    const int j0 = blockIdx.x * 64;
    for (int t = tid; t < 64 * 64; t += 256) {
        W1s[t >> 6][t & 63] = W1[t];
        ru[t >> 6][t & 63] = user[(size_t)j0 * 64 + t];
        ri[t >> 6][t & 63] = item[(size_t)j0 * 64 + t];
    }
    __syncthreads();
    for (int pass = 0; pass < 2; ++pass) {
        for (int it = 0; it < 32; ++it) {
            int idx = tid + 256 * it;
            int d = idx & 127, jl = idx >> 7;
            float scale = (pass == 0) ? rsqrtf(cs[j0 + jl]) : rsqrtf(rs[j0 + jl]);
            float v;
            if (d < 64) {
                const float(*src)[65] = (pass == 0) ? ru : ri;  // src @ W1 half
                float acc = 0.f;
#pragma unroll
                for (int k = 0; k < 64; ++k) acc += src[jl][k] * W1s[k][d];
                v = acc;
            } else {
                const float(*src)[65] = (pass == 0) ? ri : ru;  // raw tgt-of-(S@tgt) half
                v = src[jl][d - 64];
            }
            tile[d][jl] = f2bf(v * scale);
        }
        __syncthreads();
        unsigned short* Bt = (pass == 0) ? Bti : Btu;
        for (int t = tid; t < 128 * 64; t += 256) {
            int d = t >> 6, jl = t & 63;
            Bt[(size_t)d * N + j0 + jl] = tile[d][jl];
        }
        __syncthreads();
    }
}

// ---------------- main MFMA GEMM (both directions in one launch) ----------------
// P[z] = A[z] @ Bt[z]^T, A row-major bf16 [N][N], Bt [128][N] bf16, split-K atomics.
__global__ __launch_bounds__(256, 4) void gemm_kernel(
    const unsigned short* __restrict__ A0, const unsigned short* __restrict__ A1,
    const unsigned short* __restrict__ B0, const unsigned short* __restrict__ B1,
    float* __restrict__ P0, float* __restrict__ P1) {
    const unsigned short* __restrict__ A = blockIdx.z ? A1 : A0;
    const unsigned short* __restrict__ Bt = blockIdx.z ? B1 : B0;
    float* __restrict__ P = blockIdx.z ? P1 : P0;

    const int lane = threadIdx.x & 63, wave = threadIdx.x >> 6;
    const int q = lane >> 4, lm = lane & 15;
    const int m0 = blockIdx.x * 64 + wave * 16;      // 16 output rows per wave
    const int k0 = blockIdx.y * (N / KSPLIT);        // split-K chunk

    f32x4 acc[8];
#pragma unroll
    for (int n = 0; n < 8; ++n) acc[n] = (f32x4){0.f, 0.f, 0.f, 0.f};
    const unsigned short* __restrict__ ab = A + (size_t)(m0 + lm) * N + k0 + 8 * q;
    const unsigned short* __restrict__ bb = Bt + (size_t)lm * N + k0 + 8 * q;
#pragma unroll 4
    for (int ks = 0; ks < N / KSPLIT; ks += 32) {
        uint4 af = *reinterpret_cast<const uint4*>(ab + ks);
#pragma unroll
        for (int nt = 0; nt < 8; ++nt) {
            uint4 bf = *reinterpret_cast<const uint4*>(bb + (size_t)(16 * nt) * N + ks);
            acc[nt] = mfma16(af, bf, acc[nt]);
        }
    }
#pragma unroll
    for (int nt = 0; nt < 8; ++nt) {
#pragma unroll
        for (int r = 0; r < 4; ++r) {
            int row = m0 + q * 4 + r;          // C layout: row=(lane>>4)*4+reg
            int col = 16 * nt + lm;            //           col=lane&15
            atomicAdd(&P[(size_t)row * 128 + col], acc[nt][r]);
        }
    }
}

// ---------------- epilogue: scale, (g)@W2, +tgt, leaky, write ----------------
__global__ __launch_bounds__(256) void epilogue_kernel(
    const float* __restrict__ user, const float* __restrict__ item,
    const float* __restrict__ W2, const float* __restrict__ rs, const float* __restrict__ cs,
    const float* __restrict__ Pi, const float* __restrict__ Pu,
    float* __restrict__ out) {
    __shared__ float W2s[64][65];
    __shared__ float gi[4][64];
    __shared__ float gu[4][64];
    const int tid = threadIdx.x;
    for (int t = tid; t < 64 * 64; t += 256) W2s[t >> 6][t & 63] = W2[t];
    const int r4 = tid >> 6, d = tid & 63;
    for (int p = 0; p < 4; ++p) {
        const int row = blockIdx.x * 16 + p * 4 + r4;
        const float invr = rsqrtf(rs[row]);
        const float invc = rsqrtf(cs[row]);
        const float u_rd = user[(size_t)row * 64 + d];
        const float i_rd = item[(size_t)row * 64 + d];
        __syncthreads();
        gi[r4][d] = u_rd * invr * Pi[(size_t)row * 128 + 64 + d];
        gu[r4][d] = i_rd * invc * Pu[(size_t)row * 128 + 64 + d];
        __syncthreads();
        float vi = invr * Pi[(size_t)row * 128 + d] + i_rd;
        float vu = invc * Pu[(size_t)row * 128 + d] + u_rd;
#pragma unroll
        for (int e = 0; e < 64; ++e) {
            vi += gi[r4][e] * W2s[e][d];
            vu += gu[r4][e] * W2s[e][d];
        }
        vi = vi > 0.f ? vi : LRELU_ALPHA * vi;
        vu = vu > 0.f ? vu : LRELU_ALPHA * vu;
        out[(size_t)row * 64 + d] = vu;                        // updated_user (output 0)
        out[(size_t)N * 64 + (size_t)row * 64 + d] = vi;       // updated_item (output 1)
    }
}

extern "C" void kernel_launch(void* const* d_in, const int* in_sizes, int n_in,
                              void* d_out, int out_size, void* d_ws, size_t ws_size,
                              hipStream_t stream) {
    const float* user = (const float*)d_in[0];
    const float* item = (const float*)d_in[1];
    const float* adj  = (const float*)d_in[2];
    const float* W1   = (const float*)d_in[3];
    const float* W2   = (const float*)d_in[4];
    float* out = (float*)d_out;

    char* w = (char*)d_ws;
    float* Pi = (float*)w;  w += (size_t)N * 128 * 4;   // 4 MB
    float* Pu = (float*)w;  w += (size_t)N * 128 * 4;   // 4 MB
    float* rs = (float*)w;  w += (size_t)N * 4;
    float* cs = (float*)w;  w += (size_t)N * 4;
    unsigned short* Bti = (unsigned short*)w;  w += (size_t)N * 128 * 2;  // 2 MB
    unsigned short* Btu = (unsigned short*)w;  w += (size_t)N * 128 * 2;  // 2 MB
    unsigned short* adjbf = (unsigned short*)w;  w += (size_t)N * N * 2;  // 134 MB
    unsigned short* adjT  = (unsigned short*)w;                           // 134 MB

    // zero Pi, Pu, rs, cs (contiguous)
    (void)hipMemsetAsync(Pi, 0, ((size_t)2 * N * 128 + 2 * N) * 4, stream);

    pass1_kernel<<<dim3(N / 128, N / 128), 256, 0, stream>>>(adj, rs, cs, adjbf, adjT);
    prep_kernel<<<N / 64, 256, 0, stream>>>(user, item, W1, rs, cs, Bti, Btu);
    gemm_kernel<<<dim3(N / 64, KSPLIT, 2), 256, 0, stream>>>(adjbf, adjT, Bti, Btu, Pi, Pu);
    epilogue_kernel<<<N / 16, 256, 0, stream>>>(user, item, W2, rs, cs, Pi, Pu, out);
}

// Round 4
// 677.927 us; speedup vs baseline: 1.1430x; 1.1177x over previous
//
#include <hip/hip_runtime.h>
#include <hip/hip_bf16.h>

// NGCF fused propagation, N=8192, D=64.
// Pipeline:
//  pass1: read fp32 adj once -> rs, cs (row/col sums) + adjbf (bf16) + adjT (bf16 transposed)
//  prep : Bti[d][j] = invc[j]*[user@W1 | item][j][d] ; Btu[d][i] = invr[i]*[item@W1 | user][i][d]
//  gemm : Pi = adjbf @ Bti^T ; Pu = adjT @ Btu^T   (one launch, blockIdx.z selects)
//         software-pipelined register double-buffer, M=32 rows/wave, split-K atomics
//  epi  : out = leaky( inv*P[:,0:64] + (tgt_elem*inv*P[:,64:128])@W2 + tgt )

#define LRELU_ALPHA 0.2f
constexpr int N = 8192;
constexpr int KSPLIT = 8;
constexpr int KC = N / KSPLIT;   // 1024 K per block

typedef __attribute__((ext_vector_type(4))) float f32x4;
typedef __attribute__((ext_vector_type(8))) __bf16 bf16x8;

__device__ __forceinline__ unsigned short f2bf(float x) {
    unsigned u = __builtin_bit_cast(unsigned, x);
    u += 0x7fffu + ((u >> 16) & 1u);   // RNE
    return (unsigned short)(u >> 16);
}
__device__ __forceinline__ f32x4 mfma16(uint4 a, uint4 b, f32x4 c) {
    return __builtin_amdgcn_mfma_f32_16x16x32_bf16(
        __builtin_bit_cast(bf16x8, a), __builtin_bit_cast(bf16x8, b), c, 0, 0, 0);
}

// ---------------- pass1: sums + bf16 copy + bf16 transpose ----------------
__global__ __launch_bounds__(256) void pass1_kernel(
    const float* __restrict__ adj,
    float* __restrict__ rs, float* __restrict__ cs,
    unsigned short* __restrict__ adjbf, unsigned short* __restrict__ adjT) {
    __shared__ unsigned short tile[128][132];
    __shared__ float rowsumL[128];
    __shared__ float4 colpart4[8][32];
    const int tid = threadIdx.x;
    const int g32 = tid >> 5;
    const int l32 = tid & 31;
    const int r0 = blockIdx.y * 128;
    const int c0 = blockIdx.x * 128;

    float4 colacc = make_float4(0.f, 0.f, 0.f, 0.f);
#pragma unroll 4
    for (int s = 0; s < 16; ++s) {
        const int row = s * 8 + g32;
        float4 v = *reinterpret_cast<const float4*>(adj + (size_t)(r0 + row) * N + c0 + l32 * 4);
        colacc.x += v.x; colacc.y += v.y; colacc.z += v.z; colacc.w += v.w;
        ushort4 b;
        b.x = f2bf(v.x); b.y = f2bf(v.y); b.z = f2bf(v.z); b.w = f2bf(v.w);
        *reinterpret_cast<ushort4*>(&tile[row][l32 * 4]) = b;
        *reinterpret_cast<ushort4*>(adjbf + (size_t)(r0 + row) * N + c0 + l32 * 4) = b;
        float rp = (v.x + v.y) + (v.z + v.w);
#pragma unroll
        for (int off = 16; off > 0; off >>= 1) rp += __shfl_down(rp, off, 32);
        if (l32 == 0) rowsumL[row] = rp;
    }
    colpart4[g32][l32] = colacc;
    __syncthreads();

    if (tid < 128) {
        atomicAdd(rs + r0 + tid, rowsumL[tid]);
        const float* cp = (const float*)colpart4;
        float s = 0.f;
#pragma unroll
        for (int w = 0; w < 8; ++w) s += cp[w * 128 + tid];
        atomicAdd(cs + c0 + tid, s);
    }

#pragma unroll 4
    for (int s = 0; s < 16; ++s) {
        const int j = s * 8 + g32;
        ushort4 b;
        b.x = tile[l32 * 4 + 0][j];
        b.y = tile[l32 * 4 + 1][j];
        b.z = tile[l32 * 4 + 2][j];
        b.w = tile[l32 * 4 + 3][j];
        *reinterpret_cast<ushort4*>(adjT + (size_t)(c0 + j) * N + r0 + l32 * 4) = b;
    }
}

// ---------------- build the two RHS matrices (transposed, bf16) ----------------
__global__ __launch_bounds__(256) void prep_kernel(
    const float* __restrict__ user, const float* __restrict__ item,
    const float* __restrict__ W1, const float* __restrict__ rs, const float* __restrict__ cs,
    unsigned short* __restrict__ Bti, unsigned short* __restrict__ Btu) {
    __shared__ float W1s[64][65];
    __shared__ float ru[64][65];
    __shared__ float ri[64][65];
    __shared__ unsigned short tile[128][66];
    const int tid = threadIdx.x;
    const int j0 = blockIdx.x * 64;
    for (int t = tid; t < 64 * 64; t += 256) {
        W1s[t >> 6][t & 63] = W1[t];
        ru[t >> 6][t & 63] = user[(size_t)j0 * 64 + t];
        ri[t >> 6][t & 63] = item[(size_t)j0 * 64 + t];
    }
    __syncthreads();
    for (int pass = 0; pass < 2; ++pass) {
        for (int it = 0; it < 32; ++it) {
            int idx = tid + 256 * it;
            int d = idx & 127, jl = idx >> 7;
            float scale = (pass == 0) ? rsqrtf(cs[j0 + jl]) : rsqrtf(rs[j0 + jl]);
            float v;
            if (d < 64) {
                const float(*src)[65] = (pass == 0) ? ru : ri;
                float acc = 0.f;
#pragma unroll
                for (int k = 0; k < 64; ++k) acc += src[jl][k] * W1s[k][d];
                v = acc;
            } else {
                const float(*src)[65] = (pass == 0) ? ri : ru;
                v = src[jl][d - 64];
            }
            tile[d][jl] = f2bf(v * scale);
        }
        __syncthreads();
        unsigned short* Bt = (pass == 0) ? Bti : Btu;
        for (int t = tid; t < 128 * 64; t += 256) {
            int d = t >> 6, jl = t & 63;
            Bt[(size_t)d * N + j0 + jl] = tile[d][jl];
        }
        __syncthreads();
    }
}

// ---------------- main MFMA GEMM (both directions in one launch) ----------------
// P[z] = A[z] @ Bt[z]^T. A row-major bf16 [N][N], Bt [128][N] bf16.
// Explicit register software pipeline: prefetch step k+1 while MFMAing step k.
// Each wave: 32 output rows (2 m-tiles) x all 128 cols.
__global__ __launch_bounds__(256, 2) void gemm_kernel(
    const unsigned short* __restrict__ A0, const unsigned short* __restrict__ A1,
    const unsigned short* __restrict__ B0, const unsigned short* __restrict__ B1,
    float* __restrict__ P0, float* __restrict__ P1) {
    const unsigned short* __restrict__ A = blockIdx.z ? A1 : A0;
    const unsigned short* __restrict__ Bt = blockIdx.z ? B1 : B0;
    float* __restrict__ P = blockIdx.z ? P1 : P0;

    const int lane = threadIdx.x & 63, wave = threadIdx.x >> 6;
    const int q = lane >> 4, lm = lane & 15;
    const int m0 = blockIdx.x * 128 + wave * 32;   // 32 rows per wave
    const int k0 = blockIdx.y * KC;

    const unsigned short* __restrict__ ap = A + (size_t)(m0 + lm) * N + k0 + 8 * q;
    const unsigned short* __restrict__ bp = Bt + (size_t)lm * N + k0 + 8 * q;

    f32x4 acc0[8], acc1[8];
#pragma unroll
    for (int n = 0; n < 8; ++n) {
        acc0[n] = (f32x4){0.f, 0.f, 0.f, 0.f};
        acc1[n] = (f32x4){0.f, 0.f, 0.f, 0.f};
    }

    uint4 a0[2], a1[2], bf[2][8];
    a0[0] = *reinterpret_cast<const uint4*>(ap);
    a1[0] = *reinterpret_cast<const uint4*>(ap + (size_t)16 * N);
#pragma unroll
    for (int nt = 0; nt < 8; ++nt)
        bf[0][nt] = *reinterpret_cast<const uint4*>(bp + (size_t)(16 * nt) * N);

#pragma unroll 2
    for (int ks = 0; ks < KC - 32; ks += 32) {
        const int cur = (ks >> 5) & 1, nxt = cur ^ 1;
        // prefetch next step
        a0[nxt] = *reinterpret_cast<const uint4*>(ap + ks + 32);
        a1[nxt] = *reinterpret_cast<const uint4*>(ap + (size_t)16 * N + ks + 32);
#pragma unroll
        for (int nt = 0; nt < 8; ++nt)
            bf[nxt][nt] = *reinterpret_cast<const uint4*>(bp + (size_t)(16 * nt) * N + ks + 32);
        // compute current step
#pragma unroll
        for (int nt = 0; nt < 8; ++nt) {
            acc0[nt] = mfma16(a0[cur], bf[cur][nt], acc0[nt]);
            acc1[nt] = mfma16(a1[cur], bf[cur][nt], acc1[nt]);
        }
    }
    {   // last step
        const int cur = ((KC - 32) >> 5) & 1;
#pragma unroll
        for (int nt = 0; nt < 8; ++nt) {
            acc0[nt] = mfma16(a0[cur], bf[cur][nt], acc0[nt]);
            acc1[nt] = mfma16(a1[cur], bf[cur][nt], acc1[nt]);
        }
    }

#pragma unroll
    for (int nt = 0; nt < 8; ++nt) {
#pragma unroll
        for (int r = 0; r < 4; ++r) {
            const int col = 16 * nt + lm;
            const int row0 = m0 + q * 4 + r;
            atomicAdd(&P[(size_t)row0 * 128 + col], acc0[nt][r]);
            atomicAdd(&P[(size_t)(row0 + 16) * 128 + col], acc1[nt][r]);
        }
    }
}

// ---------------- epilogue: scale, (g)@W2, +tgt, leaky, write ----------------
__global__ __launch_bounds__(256) void epilogue_kernel(
    const float* __restrict__ user, const float* __restrict__ item,
    const float* __restrict__ W2, const float* __restrict__ rs, const float* __restrict__ cs,
    const float* __restrict__ Pi, const float* __restrict__ Pu,
    float* __restrict__ out) {
    __shared__ float W2s[64][65];
    __shared__ float gi[4][64];
    __shared__ float gu[4][64];
    const int tid = threadIdx.x;
    for (int t = tid; t < 64 * 64; t += 256) W2s[t >> 6][t & 63] = W2[t];
    const int r4 = tid >> 6, d = tid & 63;
    for (int p = 0; p < 4; ++p) {
        const int row = blockIdx.x * 16 + p * 4 + r4;
        const float invr = rsqrtf(rs[row]);
        const float invc = rsqrtf(cs[row]);
        const float u_rd = user[(size_t)row * 64 + d];
        const float i_rd = item[(size_t)row * 64 + d];
        __syncthreads();
        gi[r4][d] = u_rd * invr * Pi[(size_t)row * 128 + 64 + d];
        gu[r4][d] = i_rd * invc * Pu[(size_t)row * 128 + 64 + d];
        __syncthreads();
        float vi = invr * Pi[(size_t)row * 128 + d] + i_rd;
        float vu = invc * Pu[(size_t)row * 128 + d] + u_rd;
#pragma unroll
        for (int e = 0; e < 64; ++e) {
            vi += gi[r4][e] * W2s[e][d];
            vu += gu[r4][e] * W2s[e][d];
        }
        vi = vi > 0.f ? vi : LRELU_ALPHA * vi;
        vu = vu > 0.f ? vu : LRELU_ALPHA * vu;
        out[(size_t)row * 64 + d] = vu;
        out[(size_t)N * 64 + (size_t)row * 64 + d] = vi;
    }
}

extern "C" void kernel_launch(void* const* d_in, const int* in_sizes, int n_in,
                              void* d_out, int out_size, void* d_ws, size_t ws_size,
                              hipStream_t stream) {
    const float* user = (const float*)d_in[0];
    const float* item = (const float*)d_in[1];
    const float* adj  = (const float*)d_in[2];
    const float* W1   = (const float*)d_in[3];
    const float* W2   = (const float*)d_in[4];
    float* out = (float*)d_out;

    char* w = (char*)d_ws;
    float* Pi = (float*)w;  w += (size_t)N * 128 * 4;
    float* Pu = (float*)w;  w += (size_t)N * 128 * 4;
    float* rs = (float*)w;  w += (size_t)N * 4;
    float* cs = (float*)w;  w += (size_t)N * 4;
    unsigned short* Bti = (unsigned short*)w;  w += (size_t)N * 128 * 2;
    unsigned short* Btu = (unsigned short*)w;  w += (size_t)N * 128 * 2;
    unsigned short* adjbf = (unsigned short*)w;  w += (size_t)N * N * 2;
    unsigned short* adjT  = (unsigned short*)w;

    (void)hipMemsetAsync(Pi, 0, ((size_t)2 * N * 128 + 2 * N) * 4, stream);

    pass1_kernel<<<dim3(N / 128, N / 128), 256, 0, stream>>>(adj, rs, cs, adjbf, adjT);
    prep_kernel<<<N / 64, 256, 0, stream>>>(user, item, W1, rs, cs, Bti, Btu);
    gemm_kernel<<<dim3(N / 128, KSPLIT, 2), 256, 0, stream>>>(adjbf, adjT, Bti, Btu, Pi, Pu);
    epilogue_kernel<<<N / 16, 256, 0, stream>>>(user, item, W2, rs, cs, Pi, Pu, out);
}

// Round 5
// 558.934 us; speedup vs baseline: 1.3863x; 1.2129x over previous
//
#include <hip/hip_runtime.h>
#include <hip/hip_bf16.h>

// NGCF fused propagation, N=8192, D=64.
//  pass1: read fp32 adj once -> rs, cs + adjbf (bf16) + adjT (bf16 transposed, swizzled-LDS)
//  prep : Bti[d][j] = invc[j]*[user@W1 | item][j][d] ; Btu[d][i] = invr[i]*[item@W1 | user][i][d]
//  gemm : Pi = adjbf @ Bti^T ; Pu = adjT @ Btu^T  -- m97-style global_load_lds staging,
//         XOR-swizzled LDS tiles, 128x128 block tile, BK=64, split-K atomics
//  epi  : out = leaky( inv*P[:,0:64] + (tgt_elem*inv*P[:,64:128])@W2 + tgt )

#define LRELU_ALPHA 0.2f
constexpr int N = 8192;
constexpr int KSPLIT = 8;
constexpr int KC = N / KSPLIT;   // 1024 K per block, 16 BK-steps of 64

typedef __attribute__((ext_vector_type(4))) float f32x4;
typedef __attribute__((ext_vector_type(8))) __bf16 bf16x8;

__device__ __forceinline__ unsigned short f2bf(float x) {
    unsigned u = __builtin_bit_cast(unsigned, x);
    u += 0x7fffu + ((u >> 16) & 1u);   // RNE
    return (unsigned short)(u >> 16);
}
__device__ __forceinline__ f32x4 mfma16(uint4 a, uint4 b, f32x4 c) {
    return __builtin_amdgcn_mfma_f32_16x16x32_bf16(
        __builtin_bit_cast(bf16x8, a), __builtin_bit_cast(bf16x8, b), c, 0, 0, 0);
}
__device__ __forceinline__ void stage16(const void* g, void* l) {
    __builtin_amdgcn_global_load_lds(
        (const __attribute__((address_space(1))) unsigned int*)g,
        (__attribute__((address_space(3))) unsigned int*)l, 16, 0, 0);
}

// ---------------- pass1: sums + bf16 copy + bf16 transpose (swizzled) ----------------
__global__ __launch_bounds__(256) void pass1_kernel(
    const float* __restrict__ adj,
    float* __restrict__ rs, float* __restrict__ cs,
    unsigned short* __restrict__ adjbf, unsigned short* __restrict__ adjT) {
    __shared__ unsigned short tile[128 * 128];   // tile[i][cs*4+e] = adj[r0+i][c0 + (cs^(i&31))*4 + e]
    __shared__ float rowsumL[128];
    __shared__ float4 colpart4[8][32];
    const int tid = threadIdx.x;
    const int g32 = tid >> 5, l32 = tid & 31;
    const int r0 = blockIdx.y * 128, c0 = blockIdx.x * 128;

    float4 colacc = make_float4(0.f, 0.f, 0.f, 0.f);
#pragma unroll 4
    for (int s = 0; s < 16; ++s) {
        const int i = s * 8 + g32;
        float4 v = *reinterpret_cast<const float4*>(adj + (size_t)(r0 + i) * N + c0 + l32 * 4);
        colacc.x += v.x; colacc.y += v.y; colacc.z += v.z; colacc.w += v.w;
        ushort4 b;
        b.x = f2bf(v.x); b.y = f2bf(v.y); b.z = f2bf(v.z); b.w = f2bf(v.w);
        *reinterpret_cast<ushort4*>(adjbf + (size_t)(r0 + i) * N + c0 + l32 * 4) = b;
        const int csw = l32 ^ (i & 31);
        *reinterpret_cast<ushort4*>(&tile[i * 128 + csw * 4]) = b;
        float rp = (v.x + v.y) + (v.z + v.w);
#pragma unroll
        for (int off = 16; off > 0; off >>= 1) rp += __shfl_down(rp, off, 32);
        if (l32 == 0) rowsumL[i] = rp;
    }
    colpart4[g32][l32] = colacc;
    __syncthreads();

    if (tid < 128) {
        atomicAdd(rs + r0 + tid, rowsumL[tid]);
        const float* cp = (const float*)colpart4;
        float s = 0.f;
#pragma unroll
        for (int w = 0; w < 8; ++w) s += cp[w * 128 + tid];
        atomicAdd(cs + c0 + tid, s);
    }

    // transpose out: wave-uniform j, lanes span 64 consecutive i (coalesced u16 store,
    // 2-way (free) LDS banks via the swizzle)
    const int i_loc = tid & 127;
    const int jhalf = tid >> 7;
#pragma unroll 8
    for (int jj = 0; jj < 64; ++jj) {
        const int j = jhalf * 64 + jj;
        unsigned short v = tile[i_loc * 128 + (((j >> 2) ^ (i_loc & 31)) * 4) + (j & 3)];
        adjT[(size_t)(c0 + j) * N + r0 + i_loc] = v;
    }
}

// ---------------- build the two RHS matrices (transposed, bf16) ----------------
__global__ __launch_bounds__(256) void prep_kernel(
    const float* __restrict__ user, const float* __restrict__ item,
    const float* __restrict__ W1, const float* __restrict__ rs, const float* __restrict__ cs,
    unsigned short* __restrict__ Bti, unsigned short* __restrict__ Btu) {
    __shared__ float W1s[64][65];
    __shared__ float ru[64][65];
    __shared__ float ri[64][65];
    __shared__ unsigned short tile[128][66];
    const int tid = threadIdx.x;
    const int j0 = blockIdx.x * 64;
    for (int t = tid; t < 64 * 64; t += 256) {
        W1s[t >> 6][t & 63] = W1[t];
        ru[t >> 6][t & 63] = user[(size_t)j0 * 64 + t];
        ri[t >> 6][t & 63] = item[(size_t)j0 * 64 + t];
    }
    __syncthreads();
    for (int pass = 0; pass < 2; ++pass) {
        for (int it = 0; it < 32; ++it) {
            int idx = tid + 256 * it;
            int d = idx & 127, jl = idx >> 7;
            float scale = (pass == 0) ? rsqrtf(cs[j0 + jl]) : rsqrtf(rs[j0 + jl]);
            float v;
            if (d < 64) {
                const float(*src)[65] = (pass == 0) ? ru : ri;
                float acc = 0.f;
#pragma unroll
                for (int k = 0; k < 64; ++k) acc += src[jl][k] * W1s[k][d];
                v = acc;
            } else {
                const float(*src)[65] = (pass == 0) ? ri : ru;
                v = src[jl][d - 64];
            }
            tile[d][jl] = f2bf(v * scale);
        }
        __syncthreads();
        unsigned short* Bt = (pass == 0) ? Bti : Btu;
        for (int t = tid; t < 128 * 64; t += 256) {
            int d = t >> 6, jl = t & 63;
            Bt[(size_t)d * N + j0 + jl] = tile[d][jl];
        }
        __syncthreads();
    }
}

// ---------------- main MFMA GEMM: m97-style LDS staging, swizzled ----------------
// P[z] = A[z] @ Bt[z]^T. A row-major bf16 [N][N], Bt [128][N] bf16.
// Block: 128 M-rows x 128 N-cols x KC. 4 waves in 2x2; each wave 64x64 (4x4 MFMA tiles).
// LDS tiles swizzled: LDS[r][c] = G[r][k0 + (c^(r&7))*8 ...], c = 16B chunk index.
__global__ __launch_bounds__(256, 3) void gemm_kernel(
    const unsigned short* __restrict__ A0, const unsigned short* __restrict__ A1,
    const unsigned short* __restrict__ B0, const unsigned short* __restrict__ B1,
    float* __restrict__ P0, float* __restrict__ P1) {
    __shared__ unsigned short As[128 * 64];
    __shared__ unsigned short Bs[128 * 64];
    const unsigned short* __restrict__ A = blockIdx.z ? A1 : A0;
    const unsigned short* __restrict__ Bt = blockIdx.z ? B1 : B0;
    float* __restrict__ P = blockIdx.z ? P1 : P0;

    const int lane = threadIdx.x & 63, wave = threadIdx.x >> 6;
    const int q = lane >> 4, lm = lane & 15;
    const int wr = wave >> 1, wc = wave & 1;
    const int m0 = blockIdx.x * 128;
    const int kbase = blockIdx.y * KC;

    // staging coords: each wave stages rows [wave*32, wave*32+32) of both tiles,
    // 8 rows per instruction (8 lanes/row, 16 B each)
    const int sr = wave * 32 + (lane >> 3);
    const int sc = lane & 7;

    f32x4 acc[4][4];
#pragma unroll
    for (int mt = 0; mt < 4; ++mt)
#pragma unroll
        for (int nt = 0; nt < 4; ++nt) acc[mt][nt] = (f32x4){0.f, 0.f, 0.f, 0.f};

    for (int step = 0; step < KC / 64; ++step) {
        const int k0 = kbase + step * 64;
#pragma unroll
        for (int t = 0; t < 4; ++t) {
            const int r = sr + t * 8;
            const int koff = (sc ^ (r & 7)) * 8;
            stage16(A + (size_t)(m0 + r) * N + k0 + koff, &As[(wave * 32 + t * 8) * 64]);
            stage16(Bt + (size_t)r * N + k0 + koff, &Bs[(wave * 32 + t * 8) * 64]);
        }
        __syncthreads();   // compiler emits vmcnt(0) drain before s_barrier
#pragma unroll
        for (int kk = 0; kk < 2; ++kk) {
            uint4 af[4], bf[4];
#pragma unroll
            for (int mt = 0; mt < 4; ++mt) {
                const int ml = wr * 64 + mt * 16 + lm;
                af[mt] = *reinterpret_cast<const uint4*>(
                    &As[ml * 64 + (((kk * 4 + q) ^ (ml & 7)) * 8)]);
            }
#pragma unroll
            for (int nt = 0; nt < 4; ++nt) {
                const int nl = wc * 64 + nt * 16 + lm;
                bf[nt] = *reinterpret_cast<const uint4*>(
                    &Bs[nl * 64 + (((kk * 4 + q) ^ (nl & 7)) * 8)]);
            }
#pragma unroll
            for (int mt = 0; mt < 4; ++mt)
#pragma unroll
                for (int nt = 0; nt < 4; ++nt)
                    acc[mt][nt] = mfma16(af[mt], bf[nt], acc[mt][nt]);
        }
        __syncthreads();   // protect LDS from next step's staging
    }

#pragma unroll
    for (int mt = 0; mt < 4; ++mt)
#pragma unroll
        for (int nt = 0; nt < 4; ++nt)
#pragma unroll
            for (int r = 0; r < 4; ++r) {
                const int row = m0 + wr * 64 + mt * 16 + q * 4 + r;  // C: row=(lane>>4)*4+reg
                const int col = wc * 64 + nt * 16 + lm;              //    col=lane&15
                atomicAdd(&P[(size_t)row * 128 + col], acc[mt][nt][r]);
            }
}

// ---------------- epilogue: scale, (g)@W2, +tgt, leaky, write ----------------
__global__ __launch_bounds__(256) void epilogue_kernel(
    const float* __restrict__ user, const float* __restrict__ item,
    const float* __restrict__ W2, const float* __restrict__ rs, const float* __restrict__ cs,
    const float* __restrict__ Pi, const float* __restrict__ Pu,
    float* __restrict__ out) {
    __shared__ float W2s[64][65];
    __shared__ float gi[4][64];
    __shared__ float gu[4][64];
    const int tid = threadIdx.x;
    for (int t = tid; t < 64 * 64; t += 256) W2s[t >> 6][t & 63] = W2[t];
    const int r4 = tid >> 6, d = tid & 63;
    for (int p = 0; p < 4; ++p) {
        const int row = blockIdx.x * 16 + p * 4 + r4;
        const float invr = rsqrtf(rs[row]);
        const float invc = rsqrtf(cs[row]);
        const float u_rd = user[(size_t)row * 64 + d];
        const float i_rd = item[(size_t)row * 64 + d];
        __syncthreads();
        gi[r4][d] = u_rd * invr * Pi[(size_t)row * 128 + 64 + d];
        gu[r4][d] = i_rd * invc * Pu[(size_t)row * 128 + 64 + d];
        __syncthreads();
        float vi = invr * Pi[(size_t)row * 128 + d] + i_rd;
        float vu = invc * Pu[(size_t)row * 128 + d] + u_rd;
#pragma unroll
        for (int e = 0; e < 64; ++e) {
            vi += gi[r4][e] * W2s[e][d];
            vu += gu[r4][e] * W2s[e][d];
        }
        vi = vi > 0.f ? vi : LRELU_ALPHA * vi;
        vu = vu > 0.f ? vu : LRELU_ALPHA * vu;
        out[(size_t)row * 64 + d] = vu;
        out[(size_t)N * 64 + (size_t)row * 64 + d] = vi;
    }
}

extern "C" void kernel_launch(void* const* d_in, const int* in_sizes, int n_in,
                              void* d_out, int out_size, void* d_ws, size_t ws_size,
                              hipStream_t stream) {
    const float* user = (const float*)d_in[0];
    const float* item = (const float*)d_in[1];
    const float* adj  = (const float*)d_in[2];
    const float* W1   = (const float*)d_in[3];
    const float* W2   = (const float*)d_in[4];
    float* out = (float*)d_out;

    char* w = (char*)d_ws;
    float* Pi = (float*)w;  w += (size_t)N * 128 * 4;
    float* Pu = (float*)w;  w += (size_t)N * 128 * 4;
    float* rs = (float*)w;  w += (size_t)N * 4;
    float* cs = (float*)w;  w += (size_t)N * 4;
    unsigned short* Bti = (unsigned short*)w;  w += (size_t)N * 128 * 2;
    unsigned short* Btu = (unsigned short*)w;  w += (size_t)N * 128 * 2;
    unsigned short* adjbf = (unsigned short*)w;  w += (size_t)N * N * 2;
    unsigned short* adjT  = (unsigned short*)w;

    (void)hipMemsetAsync(Pi, 0, ((size_t)2 * N * 128 + 2 * N) * 4, stream);

    pass1_kernel<<<dim3(N / 128, N / 128), 256, 0, stream>>>(adj, rs, cs, adjbf, adjT);
    prep_kernel<<<N / 64, 256, 0, stream>>>(user, item, W1, rs, cs, Bti, Btu);
    gemm_kernel<<<dim3(N / 128, KSPLIT, 2), 256, 0, stream>>>(adjbf, adjT, Bti, Btu, Pi, Pu);
    epilogue_kernel<<<N / 16, 256, 0, stream>>>(user, item, W2, rs, cs, Pi, Pu, out);
}